// Round 11
// baseline (472.549 us; speedup 1.0000x reference)
//
#include <hip/hip_runtime.h>
#include <hip/hip_bf16.h>
#include <cstdint>
#include <cstddef>

#define HDIM 64
#define EPS 1e-5f
#define BN 128                     // nodes per bucket
#define BSH 7
#define NXCD 8
#define CURPAD 16                  // u32 stride between cursors: one 64B line each

typedef short bf16x8 __attribute__((ext_vector_type(8)));
typedef float f32x4  __attribute__((ext_vector_type(4)));
typedef float f4v    __attribute__((ext_vector_type(4)));
typedef unsigned u2v __attribute__((ext_vector_type(2)));
typedef unsigned u4v __attribute__((ext_vector_type(4)));

__device__ __forceinline__ unsigned bf16rn(float f) {
    unsigned u = __float_as_uint(f);
    return (u + 0x7FFFu + ((u >> 16) & 1u)) >> 16;   // round-nearest-even
}

// flipped bf16: monotone u16 encoding of bf16 order (never 0 for non-NaN input)
__device__ __forceinline__ unsigned flipbf(float f) {
    unsigned h = bf16rn(f);
    return (h & 0x8000u) ? (~h & 0xFFFFu) : (h | 0x8000u);
}

// key = flip16 << 16 ; key==0 means "never touched"
__device__ __forceinline__ unsigned unflipkey(unsigned key) {
    if (key == 0u) return 0u;                         // empty -> bf16 zero
    unsigned k = key >> 16;
    return (k & 0x8000u) ? (k & 0x7FFFu) : (~k & 0xFFFFu);
}

// ---------------- fused place: msg -> flipped-bf16 rows in bucket regions || W prep ----
// 16 threads per edge. part==0 does the two XCD-local cursor atomics (line-
// private, R8-proven) and the loc writes; positions broadcast by shfl. All 16
// lanes convert their 4 columns and store 8 B to BOTH destination rows: each
// 128 B row = 2 fully-covered cache lines -> no write amplification, and rows
// within a region are filled sequentially by one XCD (write-combining in L2).
__global__ __launch_bounds__(256) void place_kernel(
    const float* __restrict__ msg, const int* __restrict__ ei,
    unsigned* __restrict__ bcur, unsigned short* __restrict__ locs,
    unsigned short* __restrict__ rows,
    const float* __restrict__ W1, const float* __restrict__ W2,
    unsigned short* __restrict__ W1T, unsigned short* __restrict__ W2T,
    int E, int nblk, int bcap, int eblocks16) {
    int blk = blockIdx.x;
    if (blk >= eblocks16) {
        // ---- W prep ----
        int t = (blk - eblocks16) * 256 + threadIdx.x;
        if (t < 128 * 64) {
            int k = t >> 6, o = t & 63;
            W1T[o * 128 + k] = (unsigned short)bf16rn(W1[t]);
        } else {
            int t2 = t - 128 * 64;
            if (t2 < 64 * 64) {
                int k = t2 >> 6, o = t2 & 63;
                W2T[o * 64 + k] = (unsigned short)bf16rn(W2[t2]);
            }
        }
        return;
    }
    long long gid = (long long)blk * 256 + threadIdx.x;
    int e = (int)(gid >> 4);
    if (e >= E) return;
    int lane = threadIdx.x & 63;
    int part = lane & 15;
    unsigned posF = 0xFFFFFFFFu, posB = 0xFFFFFFFFu;
    if (part == 0) {
        unsigned xcd;
        asm volatile("s_getreg_b32 %0, hwreg(HW_REG_XCC_ID)" : "=s"(xcd));
        xcd &= (NXCD - 1);
        int row = ei[e];
        int col = ei[(size_t)E + e];
        unsigned cell1 = (unsigned)(col >> BSH) * NXCD + xcd;
        unsigned cell2 = (unsigned)(nblk + (row >> BSH)) * NXCD + xcd;
        unsigned p1 = atomicAdd(&bcur[(size_t)cell1 * CURPAD], 1u);
        unsigned p2 = atomicAdd(&bcur[(size_t)cell2 * CURPAD], 1u);
        posF = (p1 < (unsigned)bcap) ? cell1 * (unsigned)bcap + p1 : 0xFFFFFFFFu;
        posB = (p2 < (unsigned)bcap) ? cell2 * (unsigned)bcap + p2 : 0xFFFFFFFFu;
        if (posF != 0xFFFFFFFFu) locs[posF] = (unsigned short)(col & (BN - 1));
        if (posB != 0xFFFFFFFFu) locs[posB] = (unsigned short)(row & (BN - 1));
    }
    posF = __shfl(posF, lane & ~15);
    posB = __shfl(posB, lane & ~15);
    f4v m = __builtin_nontemporal_load((const f4v*)&msg[(size_t)e * HDIM + part * 4]);
    u2v b;
    b.x = flipbf(m.x) | (flipbf(m.y) << 16);
    b.y = flipbf(m.z) | (flipbf(m.w) << 16);
    if (posF != 0xFFFFFFFFu)
        __builtin_nontemporal_store(b, (u2v*)&rows[(size_t)posF * HDIM + part * 4]);
    if (posB != 0xFFFFFFFFu)
        __builtin_nontemporal_store(b, (u2v*)&rows[(size_t)posB * HDIM + part * 4]);
}

// ---------------- binned max: stream regions, ds_max_u32 into shared LDS acc ----------
// One WG (4 waves) per bucket, 33 KB LDS -> 4 WG/CU. Each wave streams its two
// regions: rows are CONTIGUOUS (128 B per row, sequential) so reads run at
// streaming BW; ds_max is fire-and-forget (no RMW chain). Tail -> dummy row 128.
__global__ __launch_bounds__(256) void binned_max_kernel(
    const unsigned short* __restrict__ rows, const unsigned short* __restrict__ locs,
    const unsigned* __restrict__ bcur,
    unsigned short* __restrict__ fwdB, unsigned short* __restrict__ bwdB,
    int N, int nblk, int bcap) {
    __shared__ __align__(16) unsigned acc[(BN + 1) * HDIM];   // 33,024 B
    int tid = threadIdx.x;
    int wave = tid >> 6, lane = tid & 63;
    int b = blockIdx.x;

    {
        u4v z = {};
        u4v* p = (u4v*)acc;
        for (int i = tid; i < (BN + 1) * HDIM / 4; i += 256) p[i] = z;
    }
    __syncthreads();

    unsigned accBase = (unsigned)(size_t)&acc[0];
    unsigned laneOff = accBase + ((unsigned)lane << 2);

    for (int rr = 0; rr < 2; ++rr) {
        int r = wave + rr * 4;
        size_t cell = (size_t)b * NXCD + r;
        unsigned cnt = bcur[cell * CURPAD];
        if (cnt > (unsigned)bcap) cnt = (unsigned)bcap;
        if (cnt == 0) continue;
        const unsigned short* lp = locs + cell * (unsigned)bcap;
        const unsigned short* rp = rows + cell * (unsigned)bcap * HDIM;
        for (unsigned c0 = 0; c0 < cnt; c0 += 64) {
            unsigned myloc = (c0 + (unsigned)lane < cnt) ? (unsigned)lp[c0 + lane] : 128u;
            unsigned rem = cnt - c0;
#pragma unroll
            for (int b16 = 0; b16 < 4; ++b16) {
                if ((unsigned)(b16 * 16) >= rem) break;
                unsigned short v[16];
#pragma unroll
                for (int k = 0; k < 16; ++k) {
                    unsigned j = c0 + b16 * 16 + k;
                    unsigned jc = (j < cnt) ? j : (cnt - 1);
                    v[k] = __builtin_nontemporal_load(&rp[(size_t)jc * HDIM + lane]);
                }
#pragma unroll
                for (int k = 0; k < 16; ++k) {
                    unsigned loc = __shfl(myloc, b16 * 16 + k);
                    unsigned addr = laneOff + (loc << 8);    // (loc*64+lane)*4
                    unsigned key = ((unsigned)v[k]) << 16;
                    asm volatile("ds_max_u32 %0, %1" :: "v"(addr), "v"(key));
                }
            }
        }
    }
    asm volatile("" ::: "memory");   // compiler fence: acc modified by asm
    __syncthreads();                  // drains lgkmcnt: all ds_max complete

    bool fwd = (b < nblk);
    int node0 = (fwd ? b : b - nblk) * BN;
    unsigned short* dst = fwd ? fwdB : bwdB;
    for (int i = tid; i < BN * (HDIM / 4); i += 256) {   // 8 iters
        int rrow = i >> 4, c4 = (i & 15) * 4;
        int node = node0 + rrow;
        if (node >= N) continue;
        uint4 a = *(const uint4*)&acc[rrow * HDIM + c4];
        u2v o;
        o.x = unflipkey(a.x) | (unflipkey(a.y) << 16);
        o.y = unflipkey(a.z) | (unflipkey(a.w) << 16);
        *(u2v*)(dst + (size_t)node * HDIM + c4) = o;
    }
}

// ---------------- MLP (MFMA bf16) ----------------

// y1 = concat(fwd,bwd) @ W1 + b1, fused column stats.
// mfma_f32_16x16x32_bf16: A row=lane&15,k=(lane>>4)*8+j ; C/D col=lane&15,row=(lane>>4)*4+reg
__global__ __launch_bounds__(256) void gemm1_mfma_kernel(
    const unsigned short* __restrict__ fwdB, const unsigned short* __restrict__ bwdB,
    const unsigned short* __restrict__ W1T, const float* __restrict__ b1,
    float* __restrict__ y1, float* __restrict__ sum1, float* __restrict__ sq1, int N) {
    __shared__ float wsum[4][64], wsq[4][64];
    int tid = threadIdx.x;
    int wave = tid >> 6, lane = tid & 63;
    int lrow = lane & 15, kseg = lane >> 4;
    int rbase = blockIdx.x * 64 + wave * 16;

    bf16x8 bfr[4][4];
#pragma unroll
    for (int nt = 0; nt < 4; ++nt)
#pragma unroll
        for (int kb = 0; kb < 4; ++kb)
            bfr[nt][kb] = *(const bf16x8*)(W1T + (size_t)(nt * 16 + lrow) * 128 + kb * 32 + kseg * 8);

    int r = rbase + lrow;
    bool ok = (r < N);
    size_t ro = (size_t)(ok ? r : 0) * HDIM;
    bf16x8 z = {};
    bf16x8 afr[4];
    afr[0] = *(const bf16x8*)(fwdB + ro + kseg * 8);
    afr[1] = *(const bf16x8*)(fwdB + ro + 32 + kseg * 8);
    afr[2] = *(const bf16x8*)(bwdB + ro + kseg * 8);
    afr[3] = *(const bf16x8*)(bwdB + ro + 32 + kseg * 8);
    if (!ok) { afr[0] = z; afr[1] = z; afr[2] = z; afr[3] = z; }

    f32x4 acc[4] = {};
#pragma unroll
    for (int kb = 0; kb < 4; ++kb)
#pragma unroll
        for (int nt = 0; nt < 4; ++nt)
            acc[nt] = __builtin_amdgcn_mfma_f32_16x16x32_bf16(afr[kb], bfr[nt][kb], acc[nt], 0, 0, 0);

#pragma unroll
    for (int nt = 0; nt < 4; ++nt) {
        int col = nt * 16 + lrow;
        float bias = b1[col];
        float s = 0.f, q = 0.f;
#pragma unroll
        for (int rr = 0; rr < 4; ++rr) {
            int rowi = rbase + kseg * 4 + rr;
            if (rowi < N) {
                float v = acc[nt][rr] + bias;
                y1[(size_t)rowi * HDIM + col] = v;
                s += v; q += v * v;
            }
        }
        s += __shfl_xor(s, 16); s += __shfl_xor(s, 32);
        q += __shfl_xor(q, 16); q += __shfl_xor(q, 32);
        if (kseg == 0) { wsum[wave][col] = s; wsq[wave][col] = q; }
    }
    __syncthreads();
    if (tid < 64) {
        float S = wsum[0][tid] + wsum[1][tid] + wsum[2][tid] + wsum[3][tid];
        float Q = wsq[0][tid] + wsq[1][tid] + wsq[2][tid] + wsq[3][tid];
        atomicAdd(&sum1[tid], S);
        atomicAdd(&sq1[tid], Q);
    }
}

// h1 = relu(BN1(y1)) (bf16); y2 = h1 @ W2 + b2; fused column stats.
__global__ __launch_bounds__(256) void gemm2_mfma_kernel(
    const float* __restrict__ y1, const float* __restrict__ sum1, const float* __restrict__ sq1,
    const float* __restrict__ g1, const float* __restrict__ be1,
    const unsigned short* __restrict__ W2T, const float* __restrict__ b2,
    float* __restrict__ y2, float* __restrict__ sum2, float* __restrict__ sq2, int N) {
    __shared__ float sc[64], sh[64];
    __shared__ float wsum[4][64], wsq[4][64];
    int tid = threadIdx.x;
    if (tid < 64) {
        float invN = 1.0f / (float)N;
        float mu = sum1[tid] * invN;
        float var = sq1[tid] * invN - mu * mu;
        float rs = rsqrtf(var + EPS);
        float s = rs * g1[tid];
        sc[tid] = s;
        sh[tid] = be1[tid] - mu * s;
    }
    __syncthreads();
    int wave = tid >> 6, lane = tid & 63;
    int lrow = lane & 15, kseg = lane >> 4;
    int rbase = blockIdx.x * 64 + wave * 16;

    bf16x8 bfr[4][2];
#pragma unroll
    for (int nt = 0; nt < 4; ++nt)
#pragma unroll
        for (int kb = 0; kb < 2; ++kb)
            bfr[nt][kb] = *(const bf16x8*)(W2T + (size_t)(nt * 16 + lrow) * 64 + kb * 32 + kseg * 8);

    int r = rbase + lrow;
    size_t ro = (size_t)((r < N) ? r : 0) * HDIM;
    bf16x8 afr[2];
#pragma unroll
    for (int kb = 0; kb < 2; ++kb) {
        const f4v* yp = (const f4v*)(y1 + ro + kb * 32 + kseg * 8);
        f4v u0 = yp[0], u1 = yp[1];
        int k0 = kb * 32 + kseg * 8;
        bf16x8 a;
#pragma unroll
        for (int j = 0; j < 4; ++j) {
            float h0 = fmaxf(fmaf(u0[j], sc[k0 + j], sh[k0 + j]), 0.f);
            float h1 = fmaxf(fmaf(u1[j], sc[k0 + 4 + j], sh[k0 + 4 + j]), 0.f);
            a[j] = (short)bf16rn(h0);
            a[4 + j] = (short)bf16rn(h1);
        }
        afr[kb] = a;
    }

    f32x4 acc[4] = {};
#pragma unroll
    for (int kb = 0; kb < 2; ++kb)
#pragma unroll
        for (int nt = 0; nt < 4; ++nt)
            acc[nt] = __builtin_amdgcn_mfma_f32_16x16x32_bf16(afr[kb], bfr[nt][kb], acc[nt], 0, 0, 0);

#pragma unroll
    for (int nt = 0; nt < 4; ++nt) {
        int col = nt * 16 + lrow;
        float bias = b2[col];
        float s = 0.f, q = 0.f;
#pragma unroll
        for (int rr = 0; rr < 4; ++rr) {
            int rowi = rbase + kseg * 4 + rr;
            if (rowi < N) {
                float v = acc[nt][rr] + bias;
                y2[(size_t)rowi * HDIM + col] = v;
                s += v; q += v * v;
            }
        }
        s += __shfl_xor(s, 16); s += __shfl_xor(s, 32);
        q += __shfl_xor(q, 16); q += __shfl_xor(q, 32);
        if (kseg == 0) { wsum[wave][col] = s; wsq[wave][col] = q; }
    }
    __syncthreads();
    if (tid < 64) {
        float S = wsum[0][tid] + wsum[1][tid] + wsum[2][tid] + wsum[3][tid];
        float Q = wsq[0][tid] + wsq[1][tid] + wsq[2][tid] + wsq[3][tid];
        atomicAdd(&sum2[tid], S);
        atomicAdd(&sq2[tid], Q);
    }
}

// h2 = relu(BN2(y2)); att = sigmoid(h2 @ Wa + ba)
__global__ __launch_bounds__(256) void final_kernel(
    const float* __restrict__ y2, const float* __restrict__ sum2, const float* __restrict__ sq2,
    const float* __restrict__ g2, const float* __restrict__ be2,
    const float* __restrict__ Wa, const float* __restrict__ ba,
    float* __restrict__ out_h2, float* __restrict__ out_att, int N) {
    __shared__ float sc[HDIM], sh[HDIM], wa[HDIM];
    __shared__ float bav;
    if (threadIdx.x < HDIM) {
        int c = threadIdx.x;
        float invN = 1.0f / (float)N;
        float mu = sum2[c] * invN;
        float var = sq2[c] * invN - mu * mu;
        float rstd = rsqrtf(var + EPS);
        float s = rstd * g2[c];
        sc[c] = s;
        sh[c] = be2[c] - mu * s;
        wa[c] = Wa[c];
    }
    if (threadIdx.x == 0) bav = ba[0];
    __syncthreads();
    int n = blockIdx.x * 256 + threadIdx.x;
    if (n >= N) return;

    const f4v* p = (const f4v*)&y2[(size_t)n * HDIM];
    f4v* dst = (f4v*)&out_h2[(size_t)n * HDIM];
    float att = bav;
#pragma unroll 1
    for (int kk = 0; kk < 16; ++kk) {
        f4v u = p[kk];
        f4v hv;
#pragma unroll
        for (int j = 0; j < 4; ++j) {
            int k = kk * 4 + j;
            float h = fmaxf(fmaf(u[j], sc[k], sh[k]), 0.0f);
            hv[j] = h;
            att = fmaf(h, wa[k], att);
        }
        dst[kk] = hv;
    }
    out_att[n] = 1.0f / (1.0f + expf(-att));
}

extern "C" void kernel_launch(void* const* d_in, const int* in_sizes, int n_in,
                              void* d_out, int out_size, void* d_ws, size_t ws_size,
                              hipStream_t stream) {
    const int*   ei   = (const int*)d_in[1];
    const float* msg  = (const float*)d_in[2];
    const float* W1   = (const float*)d_in[3];
    const float* b1   = (const float*)d_in[4];
    const float* g1   = (const float*)d_in[5];
    const float* be1  = (const float*)d_in[6];
    const float* W2   = (const float*)d_in[7];
    const float* b2   = (const float*)d_in[8];
    const float* g2   = (const float*)d_in[9];
    const float* be2  = (const float*)d_in[10];
    const float* Wa   = (const float*)d_in[11];
    const float* ba   = (const float*)d_in[12];

    const int N = in_sizes[0] / HDIM;
    const int E = in_sizes[1] / 2;
    const int nblk = (N + BN - 1) / BN;
    const size_t cells = (size_t)2 * nblk * NXCD;

    // workspace layout
    unsigned short* fwdB = (unsigned short*)d_ws;                 // N*64 bf16
    unsigned short* bwdB = fwdB + (size_t)N * HDIM;               // N*64 bf16
    unsigned short* W1T  = bwdB + (size_t)N * HDIM;               // 8192 bf16
    unsigned short* W2T  = W1T + 8192;                            // 4096 bf16
    float*    stats      = (float*)(W2T + 4096);                  // 256 f32
    unsigned* bcur       = (unsigned*)(stats + 256);              // cells*CURPAD u32
    unsigned short* locs = (unsigned short*)(bcur + cells * CURPAD);
    size_t locs_off      = (size_t)((char*)locs - (char*)d_ws);
    float*    y1         = (float*)d_out;                         // staged in h2 region
    float*    y2         = (float*)d_ws;                          // overlays fwdB+bwdB exactly
    float*    out_att    = (float*)d_out + (size_t)N * HDIM;

    // dynamic per-cell capacity: locs (2 B) + rows (128 B) per entry
    size_t avail = (ws_size > locs_off + 4096) ? ws_size - locs_off - 4096 : 0;
    int bcap = (int)(avail / (cells * (2 + 128)));
    bcap &= ~31;
    if (bcap > 1024) bcap = 1024;
    if (bcap < 64)   bcap = 64;
    unsigned short* rowsA = (unsigned short*)
        ((((size_t)(locs + cells * (size_t)bcap)) + 15) & ~(size_t)15);

    // zero stats + bucket cursors (contiguous)
    hipMemsetAsync(stats, 0, 256 * sizeof(float)
                             + cells * CURPAD * sizeof(unsigned), stream);

    int eblocks16 = (int)(((long long)E * 16 + 255) / 256);
    place_kernel<<<eblocks16 + 48, 256, 0, stream>>>(
        msg, ei, bcur, locs, rowsA, W1, W2, W1T, W2T, E, nblk, bcap, eblocks16);

    binned_max_kernel<<<2 * nblk, 256, 0, stream>>>(rowsA, locs, bcur,
                                                    fwdB, bwdB, N, nblk, bcap);

    int G = (N + 63) / 64;
    gemm1_mfma_kernel<<<G, 256, 0, stream>>>(fwdB, bwdB, W1T, b1, y1,
                                             stats, stats + 64, N);
    gemm2_mfma_kernel<<<G, 256, 0, stream>>>(y1, stats, stats + 64, g1, be1,
                                             W2T, b2, y2, stats + 128, stats + 192, N);
    final_kernel<<<(N + 255) / 256, 256, 0, stream>>>(y2, stats + 128, stats + 192,
                                                      g2, be2, Wa, ba,
                                                      (float*)d_out, out_att, N);
}

// Round 12
// 459.344 us; speedup vs baseline: 1.0287x; 1.0287x over previous
//
#include <hip/hip_runtime.h>
#include <hip/hip_bf16.h>
#include <cstdint>
#include <cstddef>

#define HDIM 64
#define EPS 1e-5f
#define BN 128                     // nodes per bucket
#define BSH 7
#define NXCD 8
#define BCAPX 2560                 // entries per (bucket,xcd) region (>= any bucket total)
#define CURPAD 16                  // u32 stride between cursors: one 64B line each
#define SENTE 128u                 // sentinel entry: msg row 0, loc=128 (dummy row)

typedef short bf16x8 __attribute__((ext_vector_type(8)));
typedef float f32x4  __attribute__((ext_vector_type(4)));
typedef float f4v    __attribute__((ext_vector_type(4)));
typedef unsigned u2v __attribute__((ext_vector_type(2)));
typedef unsigned u4v __attribute__((ext_vector_type(4)));

__device__ __forceinline__ unsigned bf16rn(float f) {
    unsigned u = __float_as_uint(f);
    return (u + 0x7FFFu + ((u >> 16) & 1u)) >> 16;   // round-nearest-even
}

// flipped bf16: monotone u16 encoding of bf16 order (never 0 for finite input)
__device__ __forceinline__ unsigned flipbf(float f) {
    unsigned h = bf16rn(f);
    return (h & 0x8000u) ? (~h & 0xFFFFu) : (h | 0x8000u);
}

// key = flip16 << 16 ; key==0 means "never touched"
__device__ __forceinline__ unsigned unflipkey(unsigned key) {
    if (key == 0u) return 0u;                         // empty -> bf16 zero
    unsigned k = key >> 16;
    return (k & 0x8000u) ? (k & 0x7FFFu) : (~k & 0xFFFFu);
}

// ---------------- fused prep: bucket fill || msg->flipped-bf16 (L3-temporal) || W prep --
// Fill blocks FIRST (their atomic latency drains under the convert stream).
// Convert: NT-load msg (don't pollute L3), TEMPORAL store msgB (205 MB -> stays
// resident in the 256 MB Infinity Cache for binned_max's random reads).
__global__ __launch_bounds__(256) void prep_kernel(
    const float* __restrict__ msg, unsigned short* __restrict__ msgB,
    const int* __restrict__ ei, unsigned* __restrict__ bcur,
    unsigned* __restrict__ entries,
    const float* __restrict__ W1, const float* __restrict__ W2,
    unsigned short* __restrict__ W1T, unsigned short* __restrict__ W2T,
    int E, int nblk, int eblocks, int cblocks) {
    int blk = blockIdx.x;
    if (blk < eblocks) {
        // ---- bucket fill (XCD-local regions, line-private cursors) ----
        int e = blk * 256 + threadIdx.x;
        if (e >= E) return;
        unsigned xcd;
        asm volatile("s_getreg_b32 %0, hwreg(HW_REG_XCC_ID)" : "=s"(xcd));
        xcd &= (NXCD - 1);
        int row = ei[e];
        int col = ei[(size_t)E + e];
        unsigned cell1 = (unsigned)(col >> BSH) * NXCD + xcd;
        unsigned cell2 = (unsigned)(nblk + (row >> BSH)) * NXCD + xcd;
        unsigned p1 = atomicAdd(&bcur[(size_t)cell1 * CURPAD], 1u);
        unsigned p2 = atomicAdd(&bcur[(size_t)cell2 * CURPAD], 1u);
        if (p1 < BCAPX)
            entries[(size_t)cell1 * BCAPX + p1] = ((unsigned)e << 8) | (unsigned)(col & (BN - 1));
        if (p2 < BCAPX)
            entries[(size_t)cell2 * BCAPX + p2] = ((unsigned)e << 8) | (unsigned)(row & (BN - 1));
    } else if (blk < eblocks + cblocks) {
        // ---- convert: 4 f32 -> 4 flipped-bf16 per thread, coalesced ----
        size_t i = ((size_t)(blk - eblocks) * 256 + threadIdx.x) * 4;
        size_t total = (size_t)E * HDIM;
        if (i < total) {
            f4v a = __builtin_nontemporal_load((const f4v*)&msg[i]);
            u2v o;
            o.x = flipbf(a.x) | (flipbf(a.y) << 16);
            o.y = flipbf(a.z) | (flipbf(a.w) << 16);
            *(u2v*)&msgB[i] = o;                      // TEMPORAL: keep in L3
        }
    } else {
        // ---- W prep: W1T[o][k]=bf16(W1[k][o]), W2T likewise ----
        int t = (blk - eblocks - cblocks) * 256 + threadIdx.x;
        if (t < 128 * 64) {
            int k = t >> 6, o = t & 63;
            W1T[o * 128 + k] = (unsigned short)bf16rn(W1[t]);
        } else {
            int t2 = t - 128 * 64;
            if (t2 < 64 * 64) {
                int k = t2 >> 6, o = t2 & 63;
                W2T[o * 64 + k] = (unsigned short)bf16rn(W2[t2]);
            }
        }
    }
}

// ---------------- binned max via LDS ds_max_u32 on flipped-bf16 keys ----------------
// One WG (4 waves) per bucket, 33 KB LDS -> 4 WG/CU. acc[129][64] u32 keys
// (flip16<<16), init 0. msgB rows read with TEMPORAL loads -> L3 hits (msgB
// fits the 256 MB Infinity Cache). ds_max is fire-and-forget (no RMW chain).
__global__ __launch_bounds__(256) void binned_max_kernel(
    const unsigned short* __restrict__ msgB, const unsigned* __restrict__ bcur,
    const unsigned* __restrict__ entries,
    unsigned short* __restrict__ fwdB, unsigned short* __restrict__ bwdB,
    int N, int nblk) {
    __shared__ __align__(16) unsigned acc[(BN + 1) * HDIM];   // 33,024 B
    int tid = threadIdx.x;
    int wave = tid >> 6, lane = tid & 63;
    int b = blockIdx.x;

    {
        u4v z = {};
        u4v* p = (u4v*)acc;
        for (int i = tid; i < (BN + 1) * HDIM / 4; i += 256) p[i] = z;
    }
    __syncthreads();

    unsigned accBase = (unsigned)(size_t)&acc[0];   // low 32 bits of flat = LDS offset
    unsigned laneOff = accBase + ((unsigned)lane << 2);

    for (int rr = 0; rr < 2; ++rr) {
        int r = wave + rr * 4;
        unsigned cnt = bcur[((size_t)b * NXCD + r) * CURPAD];
        if (cnt > BCAPX) cnt = BCAPX;
        const unsigned* rb = entries + ((size_t)b * NXCD + r) * BCAPX;
        for (unsigned c0 = 0; c0 < cnt; c0 += 64) {
            unsigned myent = (c0 + (unsigned)lane < cnt) ? rb[c0 + lane] : SENTE;
            unsigned rem = cnt - c0;
#pragma unroll
            for (int b16 = 0; b16 < 4; ++b16) {
                if ((unsigned)(b16 * 16) >= rem) break;
                unsigned short v[16];
#pragma unroll
                for (int k = 0; k < 16; ++k) {
                    unsigned ent = __shfl(myent, b16 * 16 + k);
                    v[k] = msgB[(size_t)(ent >> 8) * HDIM + lane];   // temporal: L3 hit
                }
#pragma unroll
                for (int k = 0; k < 16; ++k) {
                    unsigned ent = __shfl(myent, b16 * 16 + k);
                    unsigned addr = laneOff + ((ent & 255u) << 8);   // (sl*64+lane)*4
                    unsigned key = ((unsigned)v[k]) << 16;
                    asm volatile("ds_max_u32 %0, %1" :: "v"(addr), "v"(key));
                }
            }
        }
    }
    asm volatile("" ::: "memory");   // compiler fence: acc modified by asm
    __syncthreads();                  // drains lgkmcnt: all ds_max complete

    // unflip keys -> bf16, empty -> 0, coalesced 8B writes
    bool fwd = (b < nblk);
    int node0 = (fwd ? b : b - nblk) * BN;
    unsigned short* dst = fwd ? fwdB : bwdB;
    for (int i = tid; i < BN * (HDIM / 4); i += 256) {   // 8 iters
        int rrow = i >> 4, c4 = (i & 15) * 4;
        int node = node0 + rrow;
        if (node >= N) continue;
        uint4 a = *(const uint4*)&acc[rrow * HDIM + c4];
        u2v o;
        o.x = unflipkey(a.x) | (unflipkey(a.y) << 16);
        o.y = unflipkey(a.z) | (unflipkey(a.w) << 16);
        *(u2v*)(dst + (size_t)node * HDIM + c4) = o;
    }
}

// ---------------- MLP (MFMA bf16) ----------------

// y1 = concat(fwd,bwd) @ W1 + b1, fused column stats.
// mfma_f32_16x16x32_bf16: A row=lane&15,k=(lane>>4)*8+j ; C/D col=lane&15,row=(lane>>4)*4+reg
__global__ __launch_bounds__(256) void gemm1_mfma_kernel(
    const unsigned short* __restrict__ fwdB, const unsigned short* __restrict__ bwdB,
    const unsigned short* __restrict__ W1T, const float* __restrict__ b1,
    float* __restrict__ y1, float* __restrict__ sum1, float* __restrict__ sq1, int N) {
    __shared__ float wsum[4][64], wsq[4][64];
    int tid = threadIdx.x;
    int wave = tid >> 6, lane = tid & 63;
    int lrow = lane & 15, kseg = lane >> 4;
    int rbase = blockIdx.x * 64 + wave * 16;

    bf16x8 bfr[4][4];
#pragma unroll
    for (int nt = 0; nt < 4; ++nt)
#pragma unroll
        for (int kb = 0; kb < 4; ++kb)
            bfr[nt][kb] = *(const bf16x8*)(W1T + (size_t)(nt * 16 + lrow) * 128 + kb * 32 + kseg * 8);

    int r = rbase + lrow;
    bool ok = (r < N);
    size_t ro = (size_t)(ok ? r : 0) * HDIM;
    bf16x8 z = {};
    bf16x8 afr[4];
    afr[0] = *(const bf16x8*)(fwdB + ro + kseg * 8);
    afr[1] = *(const bf16x8*)(fwdB + ro + 32 + kseg * 8);
    afr[2] = *(const bf16x8*)(bwdB + ro + kseg * 8);
    afr[3] = *(const bf16x8*)(bwdB + ro + 32 + kseg * 8);
    if (!ok) { afr[0] = z; afr[1] = z; afr[2] = z; afr[3] = z; }

    f32x4 acc[4] = {};
#pragma unroll
    for (int kb = 0; kb < 4; ++kb)
#pragma unroll
        for (int nt = 0; nt < 4; ++nt)
            acc[nt] = __builtin_amdgcn_mfma_f32_16x16x32_bf16(afr[kb], bfr[nt][kb], acc[nt], 0, 0, 0);

#pragma unroll
    for (int nt = 0; nt < 4; ++nt) {
        int col = nt * 16 + lrow;
        float bias = b1[col];
        float s = 0.f, q = 0.f;
#pragma unroll
        for (int rr = 0; rr < 4; ++rr) {
            int rowi = rbase + kseg * 4 + rr;
            if (rowi < N) {
                float v = acc[nt][rr] + bias;
                y1[(size_t)rowi * HDIM + col] = v;
                s += v; q += v * v;
            }
        }
        s += __shfl_xor(s, 16); s += __shfl_xor(s, 32);
        q += __shfl_xor(q, 16); q += __shfl_xor(q, 32);
        if (kseg == 0) { wsum[wave][col] = s; wsq[wave][col] = q; }
    }
    __syncthreads();
    if (tid < 64) {
        float S = wsum[0][tid] + wsum[1][tid] + wsum[2][tid] + wsum[3][tid];
        float Q = wsq[0][tid] + wsq[1][tid] + wsq[2][tid] + wsq[3][tid];
        atomicAdd(&sum1[tid], S);
        atomicAdd(&sq1[tid], Q);
    }
}

// h1 = relu(BN1(y1)) (bf16); y2 = h1 @ W2 + b2; fused column stats.
__global__ __launch_bounds__(256) void gemm2_mfma_kernel(
    const float* __restrict__ y1, const float* __restrict__ sum1, const float* __restrict__ sq1,
    const float* __restrict__ g1, const float* __restrict__ be1,
    const unsigned short* __restrict__ W2T, const float* __restrict__ b2,
    float* __restrict__ y2, float* __restrict__ sum2, float* __restrict__ sq2, int N) {
    __shared__ float sc[64], sh[64];
    __shared__ float wsum[4][64], wsq[4][64];
    int tid = threadIdx.x;
    if (tid < 64) {
        float invN = 1.0f / (float)N;
        float mu = sum1[tid] * invN;
        float var = sq1[tid] * invN - mu * mu;
        float rs = rsqrtf(var + EPS);
        float s = rs * g1[tid];
        sc[tid] = s;
        sh[tid] = be1[tid] - mu * s;
    }
    __syncthreads();
    int wave = tid >> 6, lane = tid & 63;
    int lrow = lane & 15, kseg = lane >> 4;
    int rbase = blockIdx.x * 64 + wave * 16;

    bf16x8 bfr[4][2];
#pragma unroll
    for (int nt = 0; nt < 4; ++nt)
#pragma unroll
        for (int kb = 0; kb < 2; ++kb)
            bfr[nt][kb] = *(const bf16x8*)(W2T + (size_t)(nt * 16 + lrow) * 64 + kb * 32 + kseg * 8);

    int r = rbase + lrow;
    size_t ro = (size_t)((r < N) ? r : 0) * HDIM;
    bf16x8 afr[2];
#pragma unroll
    for (int kb = 0; kb < 2; ++kb) {
        const f4v* yp = (const f4v*)(y1 + ro + kb * 32 + kseg * 8);
        f4v u0 = yp[0], u1 = yp[1];
        int k0 = kb * 32 + kseg * 8;
        bf16x8 a;
#pragma unroll
        for (int j = 0; j < 4; ++j) {
            float h0 = fmaxf(fmaf(u0[j], sc[k0 + j], sh[k0 + j]), 0.f);
            float h1 = fmaxf(fmaf(u1[j], sc[k0 + 4 + j], sh[k0 + 4 + j]), 0.f);
            a[j] = (short)bf16rn(h0);
            a[4 + j] = (short)bf16rn(h1);
        }
        afr[kb] = a;
    }

    f32x4 acc[4] = {};
#pragma unroll
    for (int kb = 0; kb < 2; ++kb)
#pragma unroll
        for (int nt = 0; nt < 4; ++nt)
            acc[nt] = __builtin_amdgcn_mfma_f32_16x16x32_bf16(afr[kb], bfr[nt][kb], acc[nt], 0, 0, 0);

#pragma unroll
    for (int nt = 0; nt < 4; ++nt) {
        int col = nt * 16 + lrow;
        float bias = b2[col];
        float s = 0.f, q = 0.f;
#pragma unroll
        for (int rr = 0; rr < 4; ++rr) {
            int rowi = rbase + kseg * 4 + rr;
            if (rowi < N) {
                float v = acc[nt][rr] + bias;
                y2[(size_t)rowi * HDIM + col] = v;
                s += v; q += v * v;
            }
        }
        s += __shfl_xor(s, 16); s += __shfl_xor(s, 32);
        q += __shfl_xor(q, 16); q += __shfl_xor(q, 32);
        if (kseg == 0) { wsum[wave][col] = s; wsq[wave][col] = q; }
    }
    __syncthreads();
    if (tid < 64) {
        float S = wsum[0][tid] + wsum[1][tid] + wsum[2][tid] + wsum[3][tid];
        float Q = wsq[0][tid] + wsq[1][tid] + wsq[2][tid] + wsq[3][tid];
        atomicAdd(&sum2[tid], S);
        atomicAdd(&sq2[tid], Q);
    }
}

// h2 = relu(BN2(y2)); att = sigmoid(h2 @ Wa + ba)
__global__ __launch_bounds__(256) void final_kernel(
    const float* __restrict__ y2, const float* __restrict__ sum2, const float* __restrict__ sq2,
    const float* __restrict__ g2, const float* __restrict__ be2,
    const float* __restrict__ Wa, const float* __restrict__ ba,
    float* __restrict__ out_h2, float* __restrict__ out_att, int N) {
    __shared__ float sc[HDIM], sh[HDIM], wa[HDIM];
    __shared__ float bav;
    if (threadIdx.x < HDIM) {
        int c = threadIdx.x;
        float invN = 1.0f / (float)N;
        float mu = sum2[c] * invN;
        float var = sq2[c] * invN - mu * mu;
        float rstd = rsqrtf(var + EPS);
        float s = rstd * g2[c];
        sc[c] = s;
        sh[c] = be2[c] - mu * s;
        wa[c] = Wa[c];
    }
    if (threadIdx.x == 0) bav = ba[0];
    __syncthreads();
    int n = blockIdx.x * 256 + threadIdx.x;
    if (n >= N) return;

    const f4v* p = (const f4v*)&y2[(size_t)n * HDIM];
    f4v* dst = (f4v*)&out_h2[(size_t)n * HDIM];
    float att = bav;
#pragma unroll 1
    for (int kk = 0; kk < 16; ++kk) {
        f4v u = p[kk];
        f4v hv;
#pragma unroll
        for (int j = 0; j < 4; ++j) {
            int k = kk * 4 + j;
            float h = fmaxf(fmaf(u[j], sc[k], sh[k]), 0.0f);
            hv[j] = h;
            att = fmaf(h, wa[k], att);
        }
        dst[kk] = hv;
    }
    out_att[n] = 1.0f / (1.0f + expf(-att));
}

extern "C" void kernel_launch(void* const* d_in, const int* in_sizes, int n_in,
                              void* d_out, int out_size, void* d_ws, size_t ws_size,
                              hipStream_t stream) {
    const int*   ei   = (const int*)d_in[1];
    const float* msg  = (const float*)d_in[2];
    const float* W1   = (const float*)d_in[3];
    const float* b1   = (const float*)d_in[4];
    const float* g1   = (const float*)d_in[5];
    const float* be1  = (const float*)d_in[6];
    const float* W2   = (const float*)d_in[7];
    const float* b2   = (const float*)d_in[8];
    const float* g2   = (const float*)d_in[9];
    const float* be2  = (const float*)d_in[10];
    const float* Wa   = (const float*)d_in[11];
    const float* ba   = (const float*)d_in[12];

    const int N = in_sizes[0] / HDIM;
    const int E = in_sizes[1] / 2;
    const int nblk = (N + BN - 1) / BN;

    // workspace layout
    unsigned short* fwdB = (unsigned short*)d_ws;                 // N*64 bf16
    unsigned short* bwdB = fwdB + (size_t)N * HDIM;               // N*64 bf16
    unsigned short* W1T  = bwdB + (size_t)N * HDIM;               // 8192 bf16
    unsigned short* W2T  = W1T + 8192;                            // 4096 bf16
    float*    stats      = (float*)(W2T + 4096);                  // 256 f32
    unsigned* bcur       = (unsigned*)(stats + 256);              // 2*nblk*NXCD*CURPAD u32
    unsigned* entries    = bcur + (size_t)2 * nblk * NXCD * CURPAD; // 2*nblk*NXCD*BCAPX u32
    unsigned short* msgB = (unsigned short*)(entries + (size_t)2 * nblk * NXCD * BCAPX); // E*64 u16
    float*    y1         = (float*)d_out;                         // staged in h2 region
    float*    y2         = (float*)d_ws;                          // overlays fwdB+bwdB exactly
    float*    out_att    = (float*)d_out + (size_t)N * HDIM;

    // zero stats + bucket cursors (contiguous)
    hipMemsetAsync(stats, 0, 256 * sizeof(float)
                             + (size_t)2 * nblk * NXCD * CURPAD * sizeof(unsigned), stream);

    int eblocks = (E + 255) / 256;                             // fill blocks (first)
    int cblocks = (int)(((size_t)E * HDIM / 4 + 255) / 256);   // convert blocks
    int wblocks = 48;                                          // W prep blocks
    prep_kernel<<<eblocks + cblocks + wblocks, 256, 0, stream>>>(
        msg, msgB, ei, bcur, entries, W1, W2, W1T, W2T, E, nblk, eblocks, cblocks);

    binned_max_kernel<<<2 * nblk, 256, 0, stream>>>(msgB, bcur, entries, fwdB, bwdB, N, nblk);

    int G = (N + 63) / 64;
    gemm1_mfma_kernel<<<G, 256, 0, stream>>>(fwdB, bwdB, W1T, b1, y1,
                                             stats, stats + 64, N);
    gemm2_mfma_kernel<<<G, 256, 0, stream>>>(y1, stats, stats + 64, g1, be1,
                                             W2T, b2, y2, stats + 128, stats + 192, N);
    final_kernel<<<(N + 255) / 256, 256, 0, stream>>>(y2, stats + 128, stats + 192,
                                                      g2, be2, Wa, ba,
                                                      (float*)d_out, out_att, N);
}

// Round 13
// 439.261 us; speedup vs baseline: 1.0758x; 1.0457x over previous
//
#include <hip/hip_runtime.h>
#include <hip/hip_bf16.h>
#include <cstdint>
#include <cstddef>

#define HDIM 64
#define EPS 1e-5f
#define BN 128                     // nodes per bucket
#define BSH 7
#define NXCD 8
#define BCAPX 2560                 // entries per (bucket,xcd) region (>= any bucket total)
#define CURPAD 16                  // u32 stride between cursors: one 64B line each
#define SENTE 128u                 // sentinel entry: msg row 0, loc=128 (dummy row)
static const unsigned SENT = 0x007FFFFFu;   // flip(-inf)

typedef short bf16x8 __attribute__((ext_vector_type(8)));
typedef float f32x4  __attribute__((ext_vector_type(4)));
typedef float f4v    __attribute__((ext_vector_type(4)));
typedef unsigned u2v __attribute__((ext_vector_type(2)));
typedef unsigned u4v __attribute__((ext_vector_type(4)));

__device__ __forceinline__ unsigned bf16rn(float f) {
    unsigned u = __float_as_uint(f);
    return (u + 0x7FFFu + ((u >> 16) & 1u)) >> 16;   // round-nearest-even
}

__device__ __forceinline__ unsigned flipf(float f) {
    unsigned u = __float_as_uint(f);
    return u ^ (((unsigned)((int)u >> 31)) | 0x80000000u);   // monotone f32->u32
}

__device__ __forceinline__ float unflip(unsigned u) {
    if (u == SENT) return 0.0f;  // empty segment -> 0 (torch_scatter fill)
    unsigned b = (u & 0x80000000u) ? (u & 0x7FFFFFFFu) : ~u;
    return __uint_as_float(b);
}

// ---------------- fused: bucket fill (XCD-local, line-private cursors) || W prep -------
__global__ __launch_bounds__(256) void fill_kernel(
    const int* __restrict__ ei, unsigned* __restrict__ bcur,
    unsigned* __restrict__ entries,
    const float* __restrict__ W1, const float* __restrict__ W2,
    unsigned short* __restrict__ W1T, unsigned short* __restrict__ W2T,
    int E, int nblk, int eblocks) {
    int blk = blockIdx.x;
    if (blk >= eblocks) {
        // ---- W prep: W1T[o][k]=bf16(W1[k][o]), W2T likewise ----
        int t = (blk - eblocks) * 256 + threadIdx.x;
        if (t < 128 * 64) {
            int k = t >> 6, o = t & 63;
            W1T[o * 128 + k] = (unsigned short)bf16rn(W1[t]);
        } else {
            int t2 = t - 128 * 64;
            if (t2 < 64 * 64) {
                int k = t2 >> 6, o = t2 & 63;
                W2T[o * 64 + k] = (unsigned short)bf16rn(W2[t2]);
            }
        }
        return;
    }
    int e = blk * 256 + threadIdx.x;
    if (e >= E) return;
    unsigned xcd;
    asm volatile("s_getreg_b32 %0, hwreg(HW_REG_XCC_ID)" : "=s"(xcd));
    xcd &= (NXCD - 1);
    int row = ei[e];
    int col = ei[(size_t)E + e];
    unsigned cell1 = (unsigned)(col >> BSH) * NXCD + xcd;
    unsigned cell2 = (unsigned)(nblk + (row >> BSH)) * NXCD + xcd;
    unsigned p1 = atomicAdd(&bcur[(size_t)cell1 * CURPAD], 1u);
    unsigned p2 = atomicAdd(&bcur[(size_t)cell2 * CURPAD], 1u);
    if (p1 < BCAPX)
        entries[(size_t)cell1 * BCAPX + p1] = ((unsigned)e << 8) | (unsigned)(col & (BN - 1));
    if (p2 < BCAPX)
        entries[(size_t)cell2 * BCAPX + p2] = ((unsigned)e << 8) | (unsigned)(row & (BN - 1));
}

// ---------------- binned max via ds_max_u32, 2-level software pipeline ----------------
// One WG (4 waves) per bucket, 33 KB LDS -> 4 WG/CU. Per wave, per region:
//  - chunk entries (64) prefetched one chunk ahead;
//  - 16-row batches prefetched one batch ahead: next batch's global loads are
//    issued BEFORE the current batch's fire-and-forget ds_max, so HBM latency
//    hides under LDS-atomic issue + TLP instead of being serially exposed.
__global__ __launch_bounds__(256) void binned_max_kernel(
    const float* __restrict__ msg, const unsigned* __restrict__ bcur,
    const unsigned* __restrict__ entries,
    unsigned short* __restrict__ fwdB, unsigned short* __restrict__ bwdB,
    int N, int nblk) {
    __shared__ __align__(16) unsigned acc[(BN + 1) * HDIM];   // 33,024 B
    int tid = threadIdx.x;
    int wave = tid >> 6, lane = tid & 63;
    int b = blockIdx.x;

    {
        u4v sv; sv.x = SENT; sv.y = SENT; sv.z = SENT; sv.w = SENT;
        u4v* p = (u4v*)acc;
        for (int i = tid; i < (BN + 1) * HDIM / 4; i += 256) p[i] = sv;
    }
    __syncthreads();

    unsigned accBase = (unsigned)(size_t)&acc[0];   // low 32 bits of flat = LDS offset
    unsigned laneOff = accBase + ((unsigned)lane << 2);

    for (int rr = 0; rr < 2; ++rr) {
        int r = wave + rr * 4;
        unsigned cnt = bcur[((size_t)b * NXCD + r) * CURPAD];
        if (cnt > BCAPX) cnt = BCAPX;
        if (cnt == 0) continue;
        const unsigned* rb = entries + ((size_t)b * NXCD + r) * BCAPX;

        // chunk 0 entries + batch 0 rows
        unsigned cur = ((unsigned)lane < cnt) ? rb[lane] : SENTE;
        float v[16];
#pragma unroll
        for (int k = 0; k < 16; ++k) {
            unsigned ent = __shfl(cur, k);
            v[k] = __builtin_nontemporal_load(&msg[(size_t)(ent >> 8) * HDIM + lane]);
        }

        for (unsigned c0 = 0; c0 < cnt; c0 += 64) {
            unsigned rem = cnt - c0;
            // prefetch next chunk's entries (used by batch 3's row-prefetch)
            unsigned nxt = SENTE;
            bool havenxt = (c0 + 64 < cnt);
            if (havenxt)
                nxt = (c0 + 64 + (unsigned)lane < cnt) ? rb[c0 + 64 + lane] : SENTE;
#pragma unroll
            for (int b16 = 0; b16 < 4; ++b16) {
                if ((unsigned)(b16 * 16) >= rem) break;
                // prefetch next batch's rows (from cur, or next chunk's batch 0)
                bool hn = (c0 + (unsigned)((b16 + 1) * 16) < cnt);
                float vn[16];
                if (hn) {
                    unsigned src = (b16 < 3) ? cur : nxt;
                    int kb = (b16 < 3) ? (b16 + 1) * 16 : 0;
#pragma unroll
                    for (int k = 0; k < 16; ++k) {
                        unsigned ent = __shfl(src, kb + k);
                        vn[k] = __builtin_nontemporal_load(
                            &msg[(size_t)(ent >> 8) * HDIM + lane]);
                    }
                }
                // fire-and-forget LDS max for current batch
#pragma unroll
                for (int k = 0; k < 16; ++k) {
                    unsigned ent = __shfl(cur, b16 * 16 + k);
                    unsigned addr = laneOff + ((ent & 255u) << 8);   // (loc*64+lane)*4
                    asm volatile("ds_max_u32 %0, %1" :: "v"(addr), "v"(flipf(v[k])));
                }
                if (hn) {
#pragma unroll
                    for (int k = 0; k < 16; ++k) v[k] = vn[k];
                }
            }
            cur = nxt;
        }
    }
    asm volatile("" ::: "memory");   // compiler fence: acc modified by asm
    __syncthreads();                  // drains lgkmcnt: all ds_max complete

    // unflip, -inf -> 0, pack bf16, coalesced 8B writes
    bool fwd = (b < nblk);
    int node0 = (fwd ? b : b - nblk) * BN;
    unsigned short* dst = fwd ? fwdB : bwdB;
    for (int i = tid; i < BN * (HDIM / 4); i += 256) {   // 8 iters
        int rrow = i >> 4, c4 = (i & 15) * 4;
        int node = node0 + rrow;
        if (node >= N) continue;
        uint4 a = *(const uint4*)&acc[rrow * HDIM + c4];
        float v0 = unflip(a.x), v1 = unflip(a.y);
        float v2 = unflip(a.z), v3 = unflip(a.w);
        u2v o;
        o.x = bf16rn(v0) | (bf16rn(v1) << 16);
        o.y = bf16rn(v2) | (bf16rn(v3) << 16);
        *(u2v*)(dst + (size_t)node * HDIM + c4) = o;
    }
}

// ---------------- MLP (MFMA bf16) ----------------

// y1 = concat(fwd,bwd) @ W1 + b1, fused column stats.
// mfma_f32_16x16x32_bf16: A row=lane&15,k=(lane>>4)*8+j ; C/D col=lane&15,row=(lane>>4)*4+reg
__global__ __launch_bounds__(256) void gemm1_mfma_kernel(
    const unsigned short* __restrict__ fwdB, const unsigned short* __restrict__ bwdB,
    const unsigned short* __restrict__ W1T, const float* __restrict__ b1,
    float* __restrict__ y1, float* __restrict__ sum1, float* __restrict__ sq1, int N) {
    __shared__ float wsum[4][64], wsq[4][64];
    int tid = threadIdx.x;
    int wave = tid >> 6, lane = tid & 63;
    int lrow = lane & 15, kseg = lane >> 4;
    int rbase = blockIdx.x * 64 + wave * 16;

    bf16x8 bfr[4][4];
#pragma unroll
    for (int nt = 0; nt < 4; ++nt)
#pragma unroll
        for (int kb = 0; kb < 4; ++kb)
            bfr[nt][kb] = *(const bf16x8*)(W1T + (size_t)(nt * 16 + lrow) * 128 + kb * 32 + kseg * 8);

    int r = rbase + lrow;
    bool ok = (r < N);
    size_t ro = (size_t)(ok ? r : 0) * HDIM;
    bf16x8 z = {};
    bf16x8 afr[4];
    afr[0] = *(const bf16x8*)(fwdB + ro + kseg * 8);
    afr[1] = *(const bf16x8*)(fwdB + ro + 32 + kseg * 8);
    afr[2] = *(const bf16x8*)(bwdB + ro + kseg * 8);
    afr[3] = *(const bf16x8*)(bwdB + ro + 32 + kseg * 8);
    if (!ok) { afr[0] = z; afr[1] = z; afr[2] = z; afr[3] = z; }

    f32x4 acc[4] = {};
#pragma unroll
    for (int kb = 0; kb < 4; ++kb)
#pragma unroll
        for (int nt = 0; nt < 4; ++nt)
            acc[nt] = __builtin_amdgcn_mfma_f32_16x16x32_bf16(afr[kb], bfr[nt][kb], acc[nt], 0, 0, 0);

#pragma unroll
    for (int nt = 0; nt < 4; ++nt) {
        int col = nt * 16 + lrow;
        float bias = b1[col];
        float s = 0.f, q = 0.f;
#pragma unroll
        for (int rr = 0; rr < 4; ++rr) {
            int rowi = rbase + kseg * 4 + rr;
            if (rowi < N) {
                float v = acc[nt][rr] + bias;
                y1[(size_t)rowi * HDIM + col] = v;
                s += v; q += v * v;
            }
        }
        s += __shfl_xor(s, 16); s += __shfl_xor(s, 32);
        q += __shfl_xor(q, 16); q += __shfl_xor(q, 32);
        if (kseg == 0) { wsum[wave][col] = s; wsq[wave][col] = q; }
    }
    __syncthreads();
    if (tid < 64) {
        float S = wsum[0][tid] + wsum[1][tid] + wsum[2][tid] + wsum[3][tid];
        float Q = wsq[0][tid] + wsq[1][tid] + wsq[2][tid] + wsq[3][tid];
        atomicAdd(&sum1[tid], S);
        atomicAdd(&sq1[tid], Q);
    }
}

// h1 = relu(BN1(y1)) (bf16); y2 = h1 @ W2 + b2; fused column stats.
__global__ __launch_bounds__(256) void gemm2_mfma_kernel(
    const float* __restrict__ y1, const float* __restrict__ sum1, const float* __restrict__ sq1,
    const float* __restrict__ g1, const float* __restrict__ be1,
    const unsigned short* __restrict__ W2T, const float* __restrict__ b2,
    float* __restrict__ y2, float* __restrict__ sum2, float* __restrict__ sq2, int N) {
    __shared__ float sc[64], sh[64];
    __shared__ float wsum[4][64], wsq[4][64];
    int tid = threadIdx.x;
    if (tid < 64) {
        float invN = 1.0f / (float)N;
        float mu = sum1[tid] * invN;
        float var = sq1[tid] * invN - mu * mu;
        float rs = rsqrtf(var + EPS);
        float s = rs * g1[tid];
        sc[tid] = s;
        sh[tid] = be1[tid] - mu * s;
    }
    __syncthreads();
    int wave = tid >> 6, lane = tid & 63;
    int lrow = lane & 15, kseg = lane >> 4;
    int rbase = blockIdx.x * 64 + wave * 16;

    bf16x8 bfr[4][2];
#pragma unroll
    for (int nt = 0; nt < 4; ++nt)
#pragma unroll
        for (int kb = 0; kb < 2; ++kb)
            bfr[nt][kb] = *(const bf16x8*)(W2T + (size_t)(nt * 16 + lrow) * 64 + kb * 32 + kseg * 8);

    int r = rbase + lrow;
    size_t ro = (size_t)((r < N) ? r : 0) * HDIM;
    bf16x8 afr[2];
#pragma unroll
    for (int kb = 0; kb < 2; ++kb) {
        const f4v* yp = (const f4v*)(y1 + ro + kb * 32 + kseg * 8);
        f4v u0 = yp[0], u1 = yp[1];
        int k0 = kb * 32 + kseg * 8;
        bf16x8 a;
#pragma unroll
        for (int j = 0; j < 4; ++j) {
            float h0 = fmaxf(fmaf(u0[j], sc[k0 + j], sh[k0 + j]), 0.f);
            float h1 = fmaxf(fmaf(u1[j], sc[k0 + 4 + j], sh[k0 + 4 + j]), 0.f);
            a[j] = (short)bf16rn(h0);
            a[4 + j] = (short)bf16rn(h1);
        }
        afr[kb] = a;
    }

    f32x4 acc[4] = {};
#pragma unroll
    for (int kb = 0; kb < 2; ++kb)
#pragma unroll
        for (int nt = 0; nt < 4; ++nt)
            acc[nt] = __builtin_amdgcn_mfma_f32_16x16x32_bf16(afr[kb], bfr[nt][kb], acc[nt], 0, 0, 0);

#pragma unroll
    for (int nt = 0; nt < 4; ++nt) {
        int col = nt * 16 + lrow;
        float bias = b2[col];
        float s = 0.f, q = 0.f;
#pragma unroll
        for (int rr = 0; rr < 4; ++rr) {
            int rowi = rbase + kseg * 4 + rr;
            if (rowi < N) {
                float v = acc[nt][rr] + bias;
                y2[(size_t)rowi * HDIM + col] = v;
                s += v; q += v * v;
            }
        }
        s += __shfl_xor(s, 16); s += __shfl_xor(s, 32);
        q += __shfl_xor(q, 16); q += __shfl_xor(q, 32);
        if (kseg == 0) { wsum[wave][col] = s; wsq[wave][col] = q; }
    }
    __syncthreads();
    if (tid < 64) {
        float S = wsum[0][tid] + wsum[1][tid] + wsum[2][tid] + wsum[3][tid];
        float Q = wsq[0][tid] + wsq[1][tid] + wsq[2][tid] + wsq[3][tid];
        atomicAdd(&sum2[tid], S);
        atomicAdd(&sq2[tid], Q);
    }
}

// h2 = relu(BN2(y2)); att = sigmoid(h2 @ Wa + ba)
__global__ __launch_bounds__(256) void final_kernel(
    const float* __restrict__ y2, const float* __restrict__ sum2, const float* __restrict__ sq2,
    const float* __restrict__ g2, const float* __restrict__ be2,
    const float* __restrict__ Wa, const float* __restrict__ ba,
    float* __restrict__ out_h2, float* __restrict__ out_att, int N) {
    __shared__ float sc[HDIM], sh[HDIM], wa[HDIM];
    __shared__ float bav;
    if (threadIdx.x < HDIM) {
        int c = threadIdx.x;
        float invN = 1.0f / (float)N;
        float mu = sum2[c] * invN;
        float var = sq2[c] * invN - mu * mu;
        float rstd = rsqrtf(var + EPS);
        float s = rstd * g2[c];
        sc[c] = s;
        sh[c] = be2[c] - mu * s;
        wa[c] = Wa[c];
    }
    if (threadIdx.x == 0) bav = ba[0];
    __syncthreads();
    int n = blockIdx.x * 256 + threadIdx.x;
    if (n >= N) return;

    const f4v* p = (const f4v*)&y2[(size_t)n * HDIM];
    f4v* dst = (f4v*)&out_h2[(size_t)n * HDIM];
    float att = bav;
#pragma unroll 1
    for (int kk = 0; kk < 16; ++kk) {
        f4v u = p[kk];
        f4v hv;
#pragma unroll
        for (int j = 0; j < 4; ++j) {
            int k = kk * 4 + j;
            float h = fmaxf(fmaf(u[j], sc[k], sh[k]), 0.0f);
            hv[j] = h;
            att = fmaf(h, wa[k], att);
        }
        dst[kk] = hv;
    }
    out_att[n] = 1.0f / (1.0f + expf(-att));
}

extern "C" void kernel_launch(void* const* d_in, const int* in_sizes, int n_in,
                              void* d_out, int out_size, void* d_ws, size_t ws_size,
                              hipStream_t stream) {
    const int*   ei   = (const int*)d_in[1];
    const float* msg  = (const float*)d_in[2];
    const float* W1   = (const float*)d_in[3];
    const float* b1   = (const float*)d_in[4];
    const float* g1   = (const float*)d_in[5];
    const float* be1  = (const float*)d_in[6];
    const float* W2   = (const float*)d_in[7];
    const float* b2   = (const float*)d_in[8];
    const float* g2   = (const float*)d_in[9];
    const float* be2  = (const float*)d_in[10];
    const float* Wa   = (const float*)d_in[11];
    const float* ba   = (const float*)d_in[12];

    const int N = in_sizes[0] / HDIM;
    const int E = in_sizes[1] / 2;
    const int nblk = (N + BN - 1) / BN;

    // workspace layout
    unsigned short* fwdB = (unsigned short*)d_ws;                 // N*64 bf16
    unsigned short* bwdB = fwdB + (size_t)N * HDIM;               // N*64 bf16
    unsigned short* W1T  = bwdB + (size_t)N * HDIM;               // 8192 bf16
    unsigned short* W2T  = W1T + 8192;                            // 4096 bf16
    float*    stats      = (float*)(W2T + 4096);                  // 256 f32
    unsigned* bcur       = (unsigned*)(stats + 256);              // 2*nblk*NXCD*CURPAD u32
    unsigned* entries    = bcur + (size_t)2 * nblk * NXCD * CURPAD; // 2*nblk*NXCD*BCAPX u32
    float*    y1         = (float*)d_out;                         // staged in h2 region
    float*    y2         = (float*)d_ws;                          // overlays fwdB+bwdB exactly
    float*    out_att    = (float*)d_out + (size_t)N * HDIM;

    // zero stats + bucket cursors (contiguous)
    hipMemsetAsync(stats, 0, 256 * sizeof(float)
                             + (size_t)2 * nblk * NXCD * CURPAD * sizeof(unsigned), stream);

    int eblocks = (E + 255) / 256;
    fill_kernel<<<eblocks + 48, 256, 0, stream>>>(ei, bcur, entries, W1, W2,
                                                  W1T, W2T, E, nblk, eblocks);

    binned_max_kernel<<<2 * nblk, 256, 0, stream>>>(msg, bcur, entries, fwdB, bwdB, N, nblk);

    int G = (N + 63) / 64;
    gemm1_mfma_kernel<<<G, 256, 0, stream>>>(fwdB, bwdB, W1T, b1, y1,
                                             stats, stats + 64, N);
    gemm2_mfma_kernel<<<G, 256, 0, stream>>>(y1, stats, stats + 64, g1, be1,
                                             W2T, b2, y2, stats + 128, stats + 192, N);
    final_kernel<<<(N + 255) / 256, 256, 0, stream>>>(y2, stats + 128, stats + 192,
                                                      g2, be2, Wa, ba,
                                                      (float*)d_out, out_att, N);
}

// Round 14
// 428.637 us; speedup vs baseline: 1.1024x; 1.0248x over previous
//
#include <hip/hip_runtime.h>
#include <hip/hip_bf16.h>
#include <cstdint>
#include <cstddef>

#define HDIM 64
#define EPS 1e-5f
#define BN 128                     // nodes per bucket
#define BSH 7
#define NXCD 8
#define BCAPX 2560                 // entries per (bucket,xcd) region (>= any bucket total)
#define CURPAD 16                  // u32 stride between cursors: one 64B line each
#define SENTE 128u                 // sentinel entry: msg row 0, loc=128 (dummy row)
#define LSTRIDE 68                 // LDS acc row stride in u32 (pad 64->68)
static const unsigned SENT = 0x007FFFFFu;   // flip(-inf)

typedef short bf16x8 __attribute__((ext_vector_type(8)));
typedef float f32x4  __attribute__((ext_vector_type(4)));
typedef float f4v    __attribute__((ext_vector_type(4)));
typedef unsigned u2v __attribute__((ext_vector_type(2)));
typedef unsigned u4v __attribute__((ext_vector_type(4)));

__device__ __forceinline__ unsigned bf16rn(float f) {
    unsigned u = __float_as_uint(f);
    return (u + 0x7FFFu + ((u >> 16) & 1u)) >> 16;   // round-nearest-even
}

__device__ __forceinline__ unsigned flipf(float f) {
    unsigned u = __float_as_uint(f);
    return u ^ (((unsigned)((int)u >> 31)) | 0x80000000u);   // monotone f32->u32
}

__device__ __forceinline__ float unflip(unsigned u) {
    if (u == SENT) return 0.0f;  // empty segment -> 0 (torch_scatter fill)
    unsigned b = (u & 0x80000000u) ? (u & 0x7FFFFFFFu) : ~u;
    return __uint_as_float(b);
}

// ---------------- fused: bucket fill (XCD-local, line-private cursors) || W prep -------
__global__ __launch_bounds__(256) void fill_kernel(
    const int* __restrict__ ei, unsigned* __restrict__ bcur,
    unsigned* __restrict__ entries,
    const float* __restrict__ W1, const float* __restrict__ W2,
    unsigned short* __restrict__ W1T, unsigned short* __restrict__ W2T,
    int E, int nblk, int eblocks) {
    int blk = blockIdx.x;
    if (blk >= eblocks) {
        // ---- W prep: W1T[o][k]=bf16(W1[k][o]), W2T likewise ----
        int t = (blk - eblocks) * 256 + threadIdx.x;
        if (t < 128 * 64) {
            int k = t >> 6, o = t & 63;
            W1T[o * 128 + k] = (unsigned short)bf16rn(W1[t]);
        } else {
            int t2 = t - 128 * 64;
            if (t2 < 64 * 64) {
                int k = t2 >> 6, o = t2 & 63;
                W2T[o * 64 + k] = (unsigned short)bf16rn(W2[t2]);
            }
        }
        return;
    }
    int e = blk * 256 + threadIdx.x;
    if (e >= E) return;
    unsigned xcd;
    asm volatile("s_getreg_b32 %0, hwreg(HW_REG_XCC_ID)" : "=s"(xcd));
    xcd &= (NXCD - 1);
    int row = ei[e];
    int col = ei[(size_t)E + e];
    unsigned cell1 = (unsigned)(col >> BSH) * NXCD + xcd;
    unsigned cell2 = (unsigned)(nblk + (row >> BSH)) * NXCD + xcd;
    unsigned p1 = atomicAdd(&bcur[(size_t)cell1 * CURPAD], 1u);
    unsigned p2 = atomicAdd(&bcur[(size_t)cell2 * CURPAD], 1u);
    if (p1 < BCAPX)
        entries[(size_t)cell1 * BCAPX + p1] = ((unsigned)e << 8) | (unsigned)(col & (BN - 1));
    if (p2 < BCAPX)
        entries[(size_t)cell2 * BCAPX + p2] = ((unsigned)e << 8) | (unsigned)(row & (BN - 1));
}

// ---------------- binned max via ds_max_u32, WIDE loads (dwordx4, 4 rows/instr) --------
// One WG (4 waves) per bucket, 35 KB LDS -> 4 WG/CU (16 waves). Wave layout:
// 4 groups x 16 lanes; group g handles entry (s*4+g) of each 16-entry batch,
// lane's part covers 4 consecutive columns -> ONE global_load_dwordx4 fetches
// 4 rows per instruction (vs 16 dword loads): 4x fewer vmcnt slots / issue.
// ds_max remains fire-and-forget; tail entries hit dummy row 128.
__global__ __launch_bounds__(256) void binned_max_kernel(
    const float* __restrict__ msg, const unsigned* __restrict__ bcur,
    const unsigned* __restrict__ entries,
    unsigned short* __restrict__ fwdB, unsigned short* __restrict__ bwdB,
    int N, int nblk) {
    __shared__ __align__(16) unsigned acc[(BN + 1) * LSTRIDE];   // 35,088 B
    int tid = threadIdx.x;
    int wave = tid >> 6, lane = tid & 63;
    int part = lane & 15, grp = lane >> 4;
    int b = blockIdx.x;

    {
        u4v sv; sv.x = SENT; sv.y = SENT; sv.z = SENT; sv.w = SENT;
        u4v* p = (u4v*)acc;
        for (int i = tid; i < (BN + 1) * LSTRIDE / 4; i += 256) p[i] = sv;
    }
    __syncthreads();

    unsigned accBase = (unsigned)(size_t)&acc[0];   // low 32 bits of flat = LDS offset
    unsigned partOff = accBase + ((unsigned)part << 4);   // + part*4 u32

    for (int rr = 0; rr < 2; ++rr) {
        int r = wave + rr * 4;
        unsigned cnt = bcur[((size_t)b * NXCD + r) * CURPAD];
        if (cnt > BCAPX) cnt = BCAPX;
        if (cnt == 0) continue;
        const unsigned* rb = entries + ((size_t)b * NXCD + r) * BCAPX;

        for (unsigned c0 = 0; c0 < cnt; c0 += 64) {
            unsigned myent = (c0 + (unsigned)lane < cnt) ? rb[c0 + lane] : SENTE;
            unsigned rem = cnt - c0;
#pragma unroll
            for (int b16 = 0; b16 < 4; ++b16) {
                if ((unsigned)(b16 * 16) >= rem) break;
                unsigned ents[4];
                f4v m[4];
#pragma unroll
                for (int s = 0; s < 4; ++s) {
                    ents[s] = __shfl(myent, b16 * 16 + s * 4 + grp);
                    m[s] = __builtin_nontemporal_load(
                        (const f4v*)&msg[(size_t)(ents[s] >> 8) * HDIM + part * 4]);
                }
#pragma unroll
                for (int s = 0; s < 4; ++s) {
                    unsigned loc = ents[s] & 255u;
                    unsigned a0 = partOff + loc * (LSTRIDE * 4u);
                    asm volatile("ds_max_u32 %0, %1" :: "v"(a0),      "v"(flipf(m[s].x)));
                    asm volatile("ds_max_u32 %0, %1" :: "v"(a0 + 4u), "v"(flipf(m[s].y)));
                    asm volatile("ds_max_u32 %0, %1" :: "v"(a0 + 8u), "v"(flipf(m[s].z)));
                    asm volatile("ds_max_u32 %0, %1" :: "v"(a0 + 12u),"v"(flipf(m[s].w)));
                }
            }
        }
    }
    asm volatile("" ::: "memory");   // compiler fence: acc modified by asm
    __syncthreads();                  // drains lgkmcnt: all ds_max complete

    // unflip, -inf -> 0, pack bf16, coalesced 8B writes
    bool fwd = (b < nblk);
    int node0 = (fwd ? b : b - nblk) * BN;
    unsigned short* dst = fwd ? fwdB : bwdB;
    for (int i = tid; i < BN * (HDIM / 4); i += 256) {   // 8 iters
        int rrow = i >> 4, c4 = (i & 15) * 4;
        int node = node0 + rrow;
        if (node >= N) continue;
        uint4 a = *(const uint4*)&acc[rrow * LSTRIDE + c4];
        float v0 = unflip(a.x), v1 = unflip(a.y);
        float v2 = unflip(a.z), v3 = unflip(a.w);
        u2v o;
        o.x = bf16rn(v0) | (bf16rn(v1) << 16);
        o.y = bf16rn(v2) | (bf16rn(v3) << 16);
        *(u2v*)(dst + (size_t)node * HDIM + c4) = o;
    }
}

// ---------------- MLP (MFMA bf16) ----------------

// y1 = concat(fwd,bwd) @ W1 + b1, fused column stats.
// mfma_f32_16x16x32_bf16: A row=lane&15,k=(lane>>4)*8+j ; C/D col=lane&15,row=(lane>>4)*4+reg
__global__ __launch_bounds__(256) void gemm1_mfma_kernel(
    const unsigned short* __restrict__ fwdB, const unsigned short* __restrict__ bwdB,
    const unsigned short* __restrict__ W1T, const float* __restrict__ b1,
    float* __restrict__ y1, float* __restrict__ sum1, float* __restrict__ sq1, int N) {
    __shared__ float wsum[4][64], wsq[4][64];
    int tid = threadIdx.x;
    int wave = tid >> 6, lane = tid & 63;
    int lrow = lane & 15, kseg = lane >> 4;
    int rbase = blockIdx.x * 64 + wave * 16;

    bf16x8 bfr[4][4];
#pragma unroll
    for (int nt = 0; nt < 4; ++nt)
#pragma unroll
        for (int kb = 0; kb < 4; ++kb)
            bfr[nt][kb] = *(const bf16x8*)(W1T + (size_t)(nt * 16 + lrow) * 128 + kb * 32 + kseg * 8);

    int r = rbase + lrow;
    bool ok = (r < N);
    size_t ro = (size_t)(ok ? r : 0) * HDIM;
    bf16x8 z = {};
    bf16x8 afr[4];
    afr[0] = *(const bf16x8*)(fwdB + ro + kseg * 8);
    afr[1] = *(const bf16x8*)(fwdB + ro + 32 + kseg * 8);
    afr[2] = *(const bf16x8*)(bwdB + ro + kseg * 8);
    afr[3] = *(const bf16x8*)(bwdB + ro + 32 + kseg * 8);
    if (!ok) { afr[0] = z; afr[1] = z; afr[2] = z; afr[3] = z; }

    f32x4 acc[4] = {};
#pragma unroll
    for (int kb = 0; kb < 4; ++kb)
#pragma unroll
        for (int nt = 0; nt < 4; ++nt)
            acc[nt] = __builtin_amdgcn_mfma_f32_16x16x32_bf16(afr[kb], bfr[nt][kb], acc[nt], 0, 0, 0);

#pragma unroll
    for (int nt = 0; nt < 4; ++nt) {
        int col = nt * 16 + lrow;
        float bias = b1[col];
        float s = 0.f, q = 0.f;
#pragma unroll
        for (int rr = 0; rr < 4; ++rr) {
            int rowi = rbase + kseg * 4 + rr;
            if (rowi < N) {
                float v = acc[nt][rr] + bias;
                y1[(size_t)rowi * HDIM + col] = v;
                s += v; q += v * v;
            }
        }
        s += __shfl_xor(s, 16); s += __shfl_xor(s, 32);
        q += __shfl_xor(q, 16); q += __shfl_xor(q, 32);
        if (kseg == 0) { wsum[wave][col] = s; wsq[wave][col] = q; }
    }
    __syncthreads();
    if (tid < 64) {
        float S = wsum[0][tid] + wsum[1][tid] + wsum[2][tid] + wsum[3][tid];
        float Q = wsq[0][tid] + wsq[1][tid] + wsq[2][tid] + wsq[3][tid];
        atomicAdd(&sum1[tid], S);
        atomicAdd(&sq1[tid], Q);
    }
}

// h1 = relu(BN1(y1)) (bf16); y2 = h1 @ W2 + b2; fused column stats.
__global__ __launch_bounds__(256) void gemm2_mfma_kernel(
    const float* __restrict__ y1, const float* __restrict__ sum1, const float* __restrict__ sq1,
    const float* __restrict__ g1, const float* __restrict__ be1,
    const unsigned short* __restrict__ W2T, const float* __restrict__ b2,
    float* __restrict__ y2, float* __restrict__ sum2, float* __restrict__ sq2, int N) {
    __shared__ float sc[64], sh[64];
    __shared__ float wsum[4][64], wsq[4][64];
    int tid = threadIdx.x;
    if (tid < 64) {
        float invN = 1.0f / (float)N;
        float mu = sum1[tid] * invN;
        float var = sq1[tid] * invN - mu * mu;
        float rs = rsqrtf(var + EPS);
        float s = rs * g1[tid];
        sc[tid] = s;
        sh[tid] = be1[tid] - mu * s;
    }
    __syncthreads();
    int wave = tid >> 6, lane = tid & 63;
    int lrow = lane & 15, kseg = lane >> 4;
    int rbase = blockIdx.x * 64 + wave * 16;

    bf16x8 bfr[4][2];
#pragma unroll
    for (int nt = 0; nt < 4; ++nt)
#pragma unroll
        for (int kb = 0; kb < 2; ++kb)
            bfr[nt][kb] = *(const bf16x8*)(W2T + (size_t)(nt * 16 + lrow) * 64 + kb * 32 + kseg * 8);

    int r = rbase + lrow;
    size_t ro = (size_t)((r < N) ? r : 0) * HDIM;
    bf16x8 afr[2];
#pragma unroll
    for (int kb = 0; kb < 2; ++kb) {
        const f4v* yp = (const f4v*)(y1 + ro + kb * 32 + kseg * 8);
        f4v u0 = yp[0], u1 = yp[1];
        int k0 = kb * 32 + kseg * 8;
        bf16x8 a;
#pragma unroll
        for (int j = 0; j < 4; ++j) {
            float h0 = fmaxf(fmaf(u0[j], sc[k0 + j], sh[k0 + j]), 0.f);
            float h1 = fmaxf(fmaf(u1[j], sc[k0 + 4 + j], sh[k0 + 4 + j]), 0.f);
            a[j] = (short)bf16rn(h0);
            a[4 + j] = (short)bf16rn(h1);
        }
        afr[kb] = a;
    }

    f32x4 acc[4] = {};
#pragma unroll
    for (int kb = 0; kb < 2; ++kb)
#pragma unroll
        for (int nt = 0; nt < 4; ++nt)
            acc[nt] = __builtin_amdgcn_mfma_f32_16x16x32_bf16(afr[kb], bfr[nt][kb], acc[nt], 0, 0, 0);

#pragma unroll
    for (int nt = 0; nt < 4; ++nt) {
        int col = nt * 16 + lrow;
        float bias = b2[col];
        float s = 0.f, q = 0.f;
#pragma unroll
        for (int rr = 0; rr < 4; ++rr) {
            int rowi = rbase + kseg * 4 + rr;
            if (rowi < N) {
                float v = acc[nt][rr] + bias;
                y2[(size_t)rowi * HDIM + col] = v;
                s += v; q += v * v;
            }
        }
        s += __shfl_xor(s, 16); s += __shfl_xor(s, 32);
        q += __shfl_xor(q, 16); q += __shfl_xor(q, 32);
        if (kseg == 0) { wsum[wave][col] = s; wsq[wave][col] = q; }
    }
    __syncthreads();
    if (tid < 64) {
        float S = wsum[0][tid] + wsum[1][tid] + wsum[2][tid] + wsum[3][tid];
        float Q = wsq[0][tid] + wsq[1][tid] + wsq[2][tid] + wsq[3][tid];
        atomicAdd(&sum2[tid], S);
        atomicAdd(&sq2[tid], Q);
    }
}

// h2 = relu(BN2(y2)); att = sigmoid(h2 @ Wa + ba)
__global__ __launch_bounds__(256) void final_kernel(
    const float* __restrict__ y2, const float* __restrict__ sum2, const float* __restrict__ sq2,
    const float* __restrict__ g2, const float* __restrict__ be2,
    const float* __restrict__ Wa, const float* __restrict__ ba,
    float* __restrict__ out_h2, float* __restrict__ out_att, int N) {
    __shared__ float sc[HDIM], sh[HDIM], wa[HDIM];
    __shared__ float bav;
    if (threadIdx.x < HDIM) {
        int c = threadIdx.x;
        float invN = 1.0f / (float)N;
        float mu = sum2[c] * invN;
        float var = sq2[c] * invN - mu * mu;
        float rstd = rsqrtf(var + EPS);
        float s = rstd * g2[c];
        sc[c] = s;
        sh[c] = be2[c] - mu * s;
        wa[c] = Wa[c];
    }
    if (threadIdx.x == 0) bav = ba[0];
    __syncthreads();
    int n = blockIdx.x * 256 + threadIdx.x;
    if (n >= N) return;

    const f4v* p = (const f4v*)&y2[(size_t)n * HDIM];
    f4v* dst = (f4v*)&out_h2[(size_t)n * HDIM];
    float att = bav;
#pragma unroll 1
    for (int kk = 0; kk < 16; ++kk) {
        f4v u = p[kk];
        f4v hv;
#pragma unroll
        for (int j = 0; j < 4; ++j) {
            int k = kk * 4 + j;
            float h = fmaxf(fmaf(u[j], sc[k], sh[k]), 0.0f);
            hv[j] = h;
            att = fmaf(h, wa[k], att);
        }
        dst[kk] = hv;
    }
    out_att[n] = 1.0f / (1.0f + expf(-att));
}

extern "C" void kernel_launch(void* const* d_in, const int* in_sizes, int n_in,
                              void* d_out, int out_size, void* d_ws, size_t ws_size,
                              hipStream_t stream) {
    const int*   ei   = (const int*)d_in[1];
    const float* msg  = (const float*)d_in[2];
    const float* W1   = (const float*)d_in[3];
    const float* b1   = (const float*)d_in[4];
    const float* g1   = (const float*)d_in[5];
    const float* be1  = (const float*)d_in[6];
    const float* W2   = (const float*)d_in[7];
    const float* b2   = (const float*)d_in[8];
    const float* g2   = (const float*)d_in[9];
    const float* be2  = (const float*)d_in[10];
    const float* Wa   = (const float*)d_in[11];
    const float* ba   = (const float*)d_in[12];

    const int N = in_sizes[0] / HDIM;
    const int E = in_sizes[1] / 2;
    const int nblk = (N + BN - 1) / BN;

    // workspace layout
    unsigned short* fwdB = (unsigned short*)d_ws;                 // N*64 bf16
    unsigned short* bwdB = fwdB + (size_t)N * HDIM;               // N*64 bf16
    unsigned short* W1T  = bwdB + (size_t)N * HDIM;               // 8192 bf16
    unsigned short* W2T  = W1T + 8192;                            // 4096 bf16
    float*    stats      = (float*)(W2T + 4096);                  // 256 f32
    unsigned* bcur       = (unsigned*)(stats + 256);              // 2*nblk*NXCD*CURPAD u32
    unsigned* entries    = bcur + (size_t)2 * nblk * NXCD * CURPAD; // 2*nblk*NXCD*BCAPX u32
    float*    y1         = (float*)d_out;                         // staged in h2 region
    float*    y2         = (float*)d_ws;                          // overlays fwdB+bwdB exactly
    float*    out_att    = (float*)d_out + (size_t)N * HDIM;

    // zero stats + bucket cursors (contiguous)
    hipMemsetAsync(stats, 0, 256 * sizeof(float)
                             + (size_t)2 * nblk * NXCD * CURPAD * sizeof(unsigned), stream);

    int eblocks = (E + 255) / 256;
    fill_kernel<<<eblocks + 48, 256, 0, stream>>>(ei, bcur, entries, W1, W2,
                                                  W1T, W2T, E, nblk, eblocks);

    binned_max_kernel<<<2 * nblk, 256, 0, stream>>>(msg, bcur, entries, fwdB, bwdB, N, nblk);

    int G = (N + 63) / 64;
    gemm1_mfma_kernel<<<G, 256, 0, stream>>>(fwdB, bwdB, W1T, b1, y1,
                                             stats, stats + 64, N);
    gemm2_mfma_kernel<<<G, 256, 0, stream>>>(y1, stats, stats + 64, g1, be1,
                                             W2T, b2, y2, stats + 128, stats + 192, N);
    final_kernel<<<(N + 255) / 256, 256, 0, stream>>>(y2, stats + 128, stats + 192,
                                                      g2, be2, Wa, ba,
                                                      (float*)d_out, out_att, N);
}